// Round 9
// baseline (468.625 us; speedup 1.0000x reference)
//
#include <hip/hip_runtime.h>
#include <hip/hip_bf16.h>

typedef int v4i __attribute__((ext_vector_type(4)));

// ---------------------------------------------------------------------------
// Kernel 0: pack int32-widened weight -> int8 bytes  (unchanged)
// ---------------------------------------------------------------------------
__global__ __launch_bounds__(256) void pack_w_kernel(const int* __restrict__ w,
                                                     int* __restrict__ wq,
                                                     int n4) {
    int i = blockIdx.x * 256 + threadIdx.x;
    if (i < n4) {
        const int4 v = reinterpret_cast<const int4*>(w)[i];
        wq[i] = (v.x & 0xFF) | ((v.y & 0xFF) << 8) |
                ((v.z & 0xFF) << 16) | ((v.w & 0xFF) << 24);
    }
}

// ---------------------------------------------------------------------------
// Kernel 1 (fast path, K==4096): one wave per row, row in registers.
// Single read of x, wave-shuffle absmax (no LDS/barrier), quantize from regs.
// ---------------------------------------------------------------------------
__global__ __launch_bounds__(256) void quant_row4096_kernel(
    const float* __restrict__ x, int* __restrict__ aq,
    float* __restrict__ a_s) {
    const int lane = threadIdx.x & 63;
    const int wave = threadIdx.x >> 6;
    const int row  = blockIdx.x * 4 + wave;

    const float4* xr = reinterpret_cast<const float4*>(x + (size_t)row * 4096);

    float4 v[16];
#pragma unroll
    for (int i = 0; i < 16; ++i) v[i] = xr[i * 64 + lane];   // coalesced 1 KiB/instr

    float m = 0.f;
#pragma unroll
    for (int i = 0; i < 16; ++i)
        m = fmaxf(m, fmaxf(fmaxf(fabsf(v[i].x), fabsf(v[i].y)),
                           fmaxf(fabsf(v[i].z), fabsf(v[i].w))));
#pragma unroll
    for (int off = 32; off; off >>= 1) m = fmaxf(m, __shfl_xor(m, off));

    const float as = (m == 0.f) ? 1.f : (m / 127.0f);
    if (lane == 0) a_s[row] = as;

    int* aqr = aq + (size_t)row * 1024;
#pragma unroll
    for (int i = 0; i < 16; ++i) {
        int q0 = min(127, max(-128, (int)rintf(v[i].x / as)));  // IEEE div + RNE = ref
        int q1 = min(127, max(-128, (int)rintf(v[i].y / as)));
        int q2 = min(127, max(-128, (int)rintf(v[i].z / as)));
        int q3 = min(127, max(-128, (int)rintf(v[i].w / as)));
        aqr[i * 64 + lane] = (q0 & 0xFF) | ((q1 & 0xFF) << 8) |
                             ((q2 & 0xFF) << 16) | ((q3 & 0xFF) << 24);
    }
}

// ---------------------------------------------------------------------------
// Kernel 1 (generic fallback): original two-pass block-per-row version.
// ---------------------------------------------------------------------------
__global__ __launch_bounds__(256) void quant_kernel(const float* __restrict__ x,
                                                    int* __restrict__ aq,
                                                    float* __restrict__ a_s,
                                                    int K) {
    const int row = blockIdx.x;
    const float4* xr = reinterpret_cast<const float4*>(x + (size_t)row * K);
    const int K4 = K >> 2;

    float m = 0.f;
    for (int i = threadIdx.x; i < K4; i += 256) {
        float4 v = xr[i];
        m = fmaxf(m, fmaxf(fmaxf(fabsf(v.x), fabsf(v.y)),
                           fmaxf(fabsf(v.z), fabsf(v.w))));
    }
#pragma unroll
    for (int off = 32; off; off >>= 1) m = fmaxf(m, __shfl_xor(m, off));

    __shared__ float red[4];
    if ((threadIdx.x & 63) == 0) red[threadIdx.x >> 6] = m;
    __syncthreads();
    m = fmaxf(fmaxf(red[0], red[1]), fmaxf(red[2], red[3]));

    const float as = (m == 0.f) ? 1.f : (m / 127.0f);
    if (threadIdx.x == 0) a_s[row] = as;

    int* aqr = aq + (size_t)row * K4;
    for (int i = threadIdx.x; i < K4; i += 256) {
        float4 v = xr[i];
        int q0 = min(127, max(-128, (int)rintf(v.x / as)));
        int q1 = min(127, max(-128, (int)rintf(v.y / as)));
        int q2 = min(127, max(-128, (int)rintf(v.z / as)));
        int q3 = min(127, max(-128, (int)rintf(v.w / as)));
        aqr[i] = (q0 & 0xFF) | ((q1 & 0xFF) << 8) |
                 ((q2 & 0xFF) << 16) | ((q3 & 0xFF) << 24);
    }
}

// ---------------------------------------------------------------------------
// Kernel 2: int8 GEMM — byte-identical to R6 baseline (attribution: prologue
// fix only this round; 8-phase restructure is next once this anchors).
// ---------------------------------------------------------------------------
__global__ __launch_bounds__(256) void gemm_i8_kernel(
    const signed char* __restrict__ Aq,   // [M,K]
    const signed char* __restrict__ Wq,   // [N,K]
    const float* __restrict__ a_s,        // [M]
    const float* __restrict__ w_s,        // [N]
    float* __restrict__ out,              // [M,N]
    int M, int N, int K) {

    __shared__ __align__(16) signed char As[128 * 64];
    __shared__ __align__(16) signed char Bs[128 * 64];

    const int t    = threadIdx.x;
    const int lane = t & 63;
    const int wave = t >> 6;
    const int wr   = wave >> 1;   // 0..1  (M direction)
    const int wc   = wave & 1;    // 0..1  (N direction)

    const int tile_m = blockIdx.y * 128;
    const int tile_n = blockIdx.x * 128;

    v4i acc[4][4];
#pragma unroll
    for (int m = 0; m < 4; ++m)
#pragma unroll
        for (int n = 0; n < 4; ++n) acc[m][n] = (v4i){0, 0, 0, 0};

    const int srow = t >> 2;
    const int scol = (t & 3) * 16;
    const signed char* gA = Aq + (size_t)(tile_m + srow) * K + scol;
    const signed char* gB = Wq + (size_t)(tile_n + srow) * K + scol;

    signed char* lA0 = &As[t * 16];
    signed char* lA1 = &As[4096 + t * 16];
    signed char* lB0 = &Bs[t * 16];
    signed char* lB1 = &Bs[4096 + t * 16];

    const int fr = lane & 15;
    const int fq = lane >> 4;
    const int a_off = (wr * 64 + fr) * 64 + fq * 16;
    const int b_off = (wc * 64 + fr) * 64 + fq * 16;

    const size_t rowstep = (size_t)64 * K;
    const int nk = K >> 6;
    for (int kt = 0; kt < nk; ++kt) {
        __syncthreads();
        __builtin_amdgcn_global_load_lds(
            (const __attribute__((address_space(1))) void*)gA,
            (__attribute__((address_space(3))) void*)lA0, 16, 0, 0);
        __builtin_amdgcn_global_load_lds(
            (const __attribute__((address_space(1))) void*)(gA + rowstep),
            (__attribute__((address_space(3))) void*)lA1, 16, 0, 0);
        __builtin_amdgcn_global_load_lds(
            (const __attribute__((address_space(1))) void*)gB,
            (__attribute__((address_space(3))) void*)lB0, 16, 0, 0);
        __builtin_amdgcn_global_load_lds(
            (const __attribute__((address_space(1))) void*)(gB + rowstep),
            (__attribute__((address_space(3))) void*)lB1, 16, 0, 0);
        gA += 64;
        gB += 64;
        __syncthreads();

        v4i af[4], bf[4];
#pragma unroll
        for (int m = 0; m < 4; ++m)
            af[m] = *reinterpret_cast<const v4i*>(As + a_off + m * 16 * 64);
#pragma unroll
        for (int n = 0; n < 4; ++n)
            bf[n] = *reinterpret_cast<const v4i*>(Bs + b_off + n * 16 * 64);

#pragma unroll
        for (int m = 0; m < 4; ++m)
#pragma unroll
            for (int n = 0; n < 4; ++n)
                acc[m][n] = __builtin_amdgcn_mfma_i32_16x16x64_i8(
                    af[m], bf[n], acc[m][n], 0, 0, 0);
    }

#pragma unroll
    for (int n = 0; n < 4; ++n) {
        const int gcol = tile_n + wc * 64 + n * 16 + fr;
        const float ws = w_s[gcol];
#pragma unroll
        for (int m = 0; m < 4; ++m) {
            const int rbase = tile_m + wr * 64 + m * 16 + fq * 4;
#pragma unroll
            for (int j = 0; j < 4; ++j) {
                const int grow = rbase + j;
                out[(size_t)grow * N + gcol] =
                    (float)acc[m][n][j] * a_s[grow] * ws;
            }
        }
    }
}

// ---------------------------------------------------------------------------
extern "C" void kernel_launch(void* const* d_in, const int* in_sizes, int n_in,
                              void* d_out, int out_size, void* d_ws, size_t ws_size,
                              hipStream_t stream) {
    const float* x      = (const float*)d_in[0];
    const int*   w      = (const int*)d_in[1];      // int8 widened to int32
    const float* wscale = (const float*)d_in[2];

    const int N = in_sizes[2];            // OUT
    const int K = in_sizes[1] / N;        // IN
    const int M = in_sizes[0] / K;        // B*S

    signed char* aq = (signed char*)d_ws;                       // M*K int8
    signed char* wq = aq + (size_t)M * K;                       // N*K int8
    float* as_buf   = (float*)(wq + (size_t)N * K);             // M floats

    const int n4 = (N * K) >> 2;
    pack_w_kernel<<<(n4 + 255) / 256, 256, 0, stream>>>(w, (int*)wq, n4);

    if (K == 4096 && (M & 3) == 0) {
        quant_row4096_kernel<<<M / 4, 256, 0, stream>>>(x, (int*)aq, as_buf);
    } else {
        quant_kernel<<<M, 256, 0, stream>>>(x, (int*)aq, as_buf, K);
    }

    dim3 grid(N / 128, M / 128);
    gemm_i8_kernel<<<grid, 256, 0, stream>>>(aq, wq, as_buf, wscale,
                                             (float*)d_out, M, N, K);
}

// Round 11
// 435.144 us; speedup vs baseline: 1.0769x; 1.0769x over previous
//
#include <hip/hip_runtime.h>
#include <hip/hip_bf16.h>

typedef int v4i __attribute__((ext_vector_type(4)));

// ---------------------------------------------------------------------------
// Kernel 0: pack int32-widened weight -> int8 bytes  (unchanged)
// ---------------------------------------------------------------------------
__global__ __launch_bounds__(256) void pack_w_kernel(const int* __restrict__ w,
                                                     int* __restrict__ wq,
                                                     int n4) {
    int i = blockIdx.x * 256 + threadIdx.x;
    if (i < n4) {
        const int4 v = reinterpret_cast<const int4*>(w)[i];
        wq[i] = (v.x & 0xFF) | ((v.y & 0xFF) << 8) |
                ((v.z & 0xFF) << 16) | ((v.w & 0xFF) << 24);
    }
}

// ---------------------------------------------------------------------------
// Kernel 1: one wave per row, row in registers (K==4096 fast path; unchanged)
// ---------------------------------------------------------------------------
__global__ __launch_bounds__(256) void quant_row4096_kernel(
    const float* __restrict__ x, int* __restrict__ aq,
    float* __restrict__ a_s) {
    const int lane = threadIdx.x & 63;
    const int wave = threadIdx.x >> 6;
    const int row  = blockIdx.x * 4 + wave;

    const float4* xr = reinterpret_cast<const float4*>(x + (size_t)row * 4096);

    float4 v[16];
#pragma unroll
    for (int i = 0; i < 16; ++i) v[i] = xr[i * 64 + lane];

    float m = 0.f;
#pragma unroll
    for (int i = 0; i < 16; ++i)
        m = fmaxf(m, fmaxf(fmaxf(fabsf(v[i].x), fabsf(v[i].y)),
                           fmaxf(fabsf(v[i].z), fabsf(v[i].w))));
#pragma unroll
    for (int off = 32; off; off >>= 1) m = fmaxf(m, __shfl_xor(m, off));

    const float as = (m == 0.f) ? 1.f : (m / 127.0f);
    if (lane == 0) a_s[row] = as;

    int* aqr = aq + (size_t)row * 1024;
#pragma unroll
    for (int i = 0; i < 16; ++i) {
        int q0 = min(127, max(-128, (int)rintf(v[i].x / as)));
        int q1 = min(127, max(-128, (int)rintf(v[i].y / as)));
        int q2 = min(127, max(-128, (int)rintf(v[i].z / as)));
        int q3 = min(127, max(-128, (int)rintf(v[i].w / as)));
        aqr[i * 64 + lane] = (q0 & 0xFF) | ((q1 & 0xFF) << 8) |
                             ((q2 & 0xFF) << 16) | ((q3 & 0xFF) << 24);
    }
}

// ---------------------------------------------------------------------------
// Kernel 1 fallback (generic K)
// ---------------------------------------------------------------------------
__global__ __launch_bounds__(256) void quant_kernel(const float* __restrict__ x,
                                                    int* __restrict__ aq,
                                                    float* __restrict__ a_s,
                                                    int K) {
    const int row = blockIdx.x;
    const float4* xr = reinterpret_cast<const float4*>(x + (size_t)row * K);
    const int K4 = K >> 2;

    float m = 0.f;
    for (int i = threadIdx.x; i < K4; i += 256) {
        float4 v = xr[i];
        m = fmaxf(m, fmaxf(fmaxf(fabsf(v.x), fabsf(v.y)),
                           fmaxf(fabsf(v.z), fabsf(v.w))));
    }
#pragma unroll
    for (int off = 32; off; off >>= 1) m = fmaxf(m, __shfl_xor(m, off));

    __shared__ float red[4];
    if ((threadIdx.x & 63) == 0) red[threadIdx.x >> 6] = m;
    __syncthreads();
    m = fmaxf(fmaxf(red[0], red[1]), fmaxf(red[2], red[3]));

    const float as = (m == 0.f) ? 1.f : (m / 127.0f);
    if (threadIdx.x == 0) a_s[row] = as;

    int* aqr = aq + (size_t)row * K4;
    for (int i = threadIdx.x; i < K4; i += 256) {
        float4 v = xr[i];
        int q0 = min(127, max(-128, (int)rintf(v.x / as)));
        int q1 = min(127, max(-128, (int)rintf(v.y / as)));
        int q2 = min(127, max(-128, (int)rintf(v.z / as)));
        int q3 = min(127, max(-128, (int)rintf(v.w / as)));
        aqr[i] = (q0 & 0xFF) | ((q1 & 0xFF) << 8) |
                 ((q2 & 0xFF) << 16) | ((q3 & 0xFF) << 24);
    }
}

// ---------------------------------------------------------------------------
// Kernel 2: int8 GEMM, 256x256 tile, BK=128 bytes, 8 waves (2Mx4N),
// phase-split MFMA + raw barriers + setprio (T5), LDS XOR-swizzle (T2),
// tile-top staging issue with boundary drain, XCD swizzle (T1).
//
// LDS map per slot (64 KB): A[256][128] at +0, B[256][128] at +32768.
// Swizzle (region offset p): phys = p ^ ((row&7)<<4), row = p>>7.
//   - ds_read spreads over all 8 4-bank groups (b128 optimum; was 4 groups).
//   - global_load_lds dest stays LINEAR; source col pre-swizzled:
//     scol = ((t&7) ^ ((t>>3)&7))<<4  (rule #21: both-sides-or-neither).
// Sync: per sub-phase raw s_barrier pairs; ONE vmcnt(0) per K-tile at the
// boundary — staging was issued a full tile (64 MFMA) earlier, so the drain
// is near-free (unlike m97's issue-then-drain-immediately stall).
// ---------------------------------------------------------------------------
__global__ __launch_bounds__(512, 2) void gemm_i8_8p(
    const signed char* __restrict__ Aq,   // [M,K]
    const signed char* __restrict__ Wq,   // [N,K]
    const float* __restrict__ a_s,        // [M]
    const float* __restrict__ w_s,        // [N]
    float* __restrict__ out,              // [M,N]
    int M, int N, int K) {

    __shared__ __align__(16) signed char lds[131072];

    const int th   = threadIdx.x;
    const int lane = th & 63;
    const int wave = th >> 6;
    const int wr   = wave >> 2;          // 0..1 (M)
    const int wc   = wave & 3;           // 0..3 (N)
    const int fr   = lane & 15;
    const int fq   = lane >> 4;
    const int sw   = (fr & 7) << 4;      // per-lane swizzle XOR (row&7 == fr&7)

    // XCD-aware bijective block swizzle (nwg % 8 == 0 here)
    const int nmt = M >> 8;
    const int nnt = N >> 8;
    const int nwg = nmt * nnt;
    int id = blockIdx.x;
    if ((nwg & 7) == 0) id = (id & 7) * (nwg >> 3) + (id >> 3);
    const int tile_n = (id / nmt) << 8;   // consecutive ids share B-panel
    const int tile_m = (id % nmt) << 8;

    // staging geometry: thread th stages 16B of row (c*64 + th>>3),
    // src col pre-swizzled so linear LDS dest yields swizzled contents.
    const int srow8 = th >> 3;                               // 0..63
    const int scol  = (((th & 7) ^ (srow8 & 7)) << 4);       // 0..112
    const signed char* ga[4];
    const signed char* gb[4];
#pragma unroll
    for (int c = 0; c < 4; ++c) {
        ga[c] = Aq + (size_t)(tile_m + c * 64 + srow8) * K + scol;
        gb[c] = Wq + (size_t)(tile_n + c * 64 + srow8) * K + scol;
    }
    const int ldst = th << 4;

    v4i acc[8][4];
#pragma unroll
    for (int i = 0; i < 8; ++i)
#pragma unroll
        for (int j = 0; j < 4; ++j) acc[i][j] = (v4i){0, 0, 0, 0};

    const int abase = (wr * 128 + fr) * 128 + fq * 16;  // + m*2048 + ks*64
    const int bbase = (wc * 64  + fr) * 128 + fq * 16;  // + n*2048 + ks*64
    const int nkt   = K >> 7;

    // prologue: stage tile 0 -> slot 0, full drain once
#pragma unroll
    for (int c = 0; c < 4; ++c) {
        __builtin_amdgcn_global_load_lds(
            (const __attribute__((address_space(1))) void*)(ga[c]),
            (__attribute__((address_space(3))) void*)&lds[c * 8192 + ldst], 16, 0, 0);
        __builtin_amdgcn_global_load_lds(
            (const __attribute__((address_space(1))) void*)(gb[c]),
            (__attribute__((address_space(3))) void*)&lds[32768 + c * 8192 + ldst], 16, 0, 0);
    }
    asm volatile("s_waitcnt vmcnt(0)" ::: "memory");
    __builtin_amdgcn_s_barrier();

    for (int kt = 0; kt < nkt; ++kt) {
        const int cur = kt & 1;
        const int cA  = cur * 65536;
        const int cB  = cA + 32768;
        const int nA  = (cur ^ 1) * 65536;

        // issue next tile's 8 staging loads NOW (drained at tile boundary,
        // a full 64-MFMA tile later)
        if (kt + 1 < nkt) {
            const int koff = (kt + 1) << 7;
#pragma unroll
            for (int c = 0; c < 4; ++c) {
                __builtin_amdgcn_global_load_lds(
                    (const __attribute__((address_space(1))) void*)(ga[c] + koff),
                    (__attribute__((address_space(3))) void*)&lds[nA + c * 8192 + ldst], 16, 0, 0);
                __builtin_amdgcn_global_load_lds(
                    (const __attribute__((address_space(1))) void*)(gb[c] + koff),
                    (__attribute__((address_space(3))) void*)&lds[nA + 32768 + c * 8192 + ldst], 16, 0, 0);
            }
        }

        v4i a[4][2], b[2][2];
#pragma unroll
        for (int mg = 0; mg < 2; ++mg) {
            // ---- sub-phase 0: load A frags (this m-group) + B n0-1; MFMA ng=0
#pragma unroll
            for (int mm = 0; mm < 4; ++mm)
#pragma unroll
                for (int ks = 0; ks < 2; ++ks)
                    a[mm][ks] = *reinterpret_cast<const v4i*>(
                        &lds[cA + ((abase + (mg * 4 + mm) * 2048 + ks * 64) ^ sw)]);
#pragma unroll
            for (int nn = 0; nn < 2; ++nn)
#pragma unroll
                for (int ks = 0; ks < 2; ++ks)
                    b[nn][ks] = *reinterpret_cast<const v4i*>(
                        &lds[cB + ((bbase + nn * 2048 + ks * 64) ^ sw)]);
            __builtin_amdgcn_s_barrier();
            __builtin_amdgcn_s_setprio(1);
#pragma unroll
            for (int mm = 0; mm < 4; ++mm)
#pragma unroll
                for (int nn = 0; nn < 2; ++nn)
#pragma unroll
                    for (int ks = 0; ks < 2; ++ks)
                        acc[mg * 4 + mm][nn] = __builtin_amdgcn_mfma_i32_16x16x64_i8(
                            a[mm][ks], b[nn][ks], acc[mg * 4 + mm][nn], 0, 0, 0);
            __builtin_amdgcn_s_setprio(0);
            __builtin_amdgcn_s_barrier();
            // ---- sub-phase 1: load B n2-3; MFMA ng=1
#pragma unroll
            for (int nn = 0; nn < 2; ++nn)
#pragma unroll
                for (int ks = 0; ks < 2; ++ks)
                    b[nn][ks] = *reinterpret_cast<const v4i*>(
                        &lds[cB + ((bbase + (2 + nn) * 2048 + ks * 64) ^ sw)]);
            __builtin_amdgcn_s_barrier();
            __builtin_amdgcn_s_setprio(1);
#pragma unroll
            for (int mm = 0; mm < 4; ++mm)
#pragma unroll
                for (int nn = 0; nn < 2; ++nn)
#pragma unroll
                    for (int ks = 0; ks < 2; ++ks)
                        acc[mg * 4 + mm][2 + nn] = __builtin_amdgcn_mfma_i32_16x16x64_i8(
                            a[mm][ks], b[nn][ks], acc[mg * 4 + mm][2 + nn], 0, 0, 0);
            __builtin_amdgcn_s_setprio(0);
            if (mg == 1 && kt + 1 < nkt)
                asm volatile("s_waitcnt vmcnt(0)" ::: "memory");
            __builtin_amdgcn_s_barrier();
        }
    }

    // epilogue: C/D layout col=lane&15, row=(lane>>4)*4+reg (m89-verified)
#pragma unroll
    for (int n = 0; n < 4; ++n) {
        const int gcol = tile_n + wc * 64 + n * 16 + fr;
        const float ws = w_s[gcol];
#pragma unroll
        for (int m = 0; m < 8; ++m) {
            const int rbase = tile_m + wr * 128 + m * 16 + fq * 4;
#pragma unroll
            for (int j = 0; j < 4; ++j) {
                const int grow = rbase + j;
                out[(size_t)grow * N + gcol] =
                    (float)acc[m][n][j] * a_s[grow] * ws;
            }
        }
    }
}

// ---------------------------------------------------------------------------
// Fallback GEMM (R6 128x128, known-correct) for non-conforming shapes
// ---------------------------------------------------------------------------
__global__ __launch_bounds__(256) void gemm_i8_kernel(
    const signed char* __restrict__ Aq, const signed char* __restrict__ Wq,
    const float* __restrict__ a_s, const float* __restrict__ w_s,
    float* __restrict__ out, int M, int N, int K) {

    __shared__ __align__(16) signed char As[128 * 64];
    __shared__ __align__(16) signed char Bs[128 * 64];

    const int t = threadIdx.x, lane = t & 63, wave = t >> 6;
    const int wr = wave >> 1, wc = wave & 1;
    const int tile_m = blockIdx.y * 128, tile_n = blockIdx.x * 128;

    v4i acc[4][4];
#pragma unroll
    for (int m = 0; m < 4; ++m)
#pragma unroll
        for (int n = 0; n < 4; ++n) acc[m][n] = (v4i){0, 0, 0, 0};

    const int srow = t >> 2, scol = (t & 3) * 16;
    const signed char* gA = Aq + (size_t)(tile_m + srow) * K + scol;
    const signed char* gB = Wq + (size_t)(tile_n + srow) * K + scol;
    signed char* lA0 = &As[t * 16]; signed char* lA1 = &As[4096 + t * 16];
    signed char* lB0 = &Bs[t * 16]; signed char* lB1 = &Bs[4096 + t * 16];

    const int fr = lane & 15, fq = lane >> 4;
    const int a_off = (wr * 64 + fr) * 64 + fq * 16;
    const int b_off = (wc * 64 + fr) * 64 + fq * 16;
    const size_t rowstep = (size_t)64 * K;
    const int nk = K >> 6;
    for (int kt = 0; kt < nk; ++kt) {
        __syncthreads();
        __builtin_amdgcn_global_load_lds((const __attribute__((address_space(1))) void*)gA,
            (__attribute__((address_space(3))) void*)lA0, 16, 0, 0);
        __builtin_amdgcn_global_load_lds((const __attribute__((address_space(1))) void*)(gA + rowstep),
            (__attribute__((address_space(3))) void*)lA1, 16, 0, 0);
        __builtin_amdgcn_global_load_lds((const __attribute__((address_space(1))) void*)gB,
            (__attribute__((address_space(3))) void*)lB0, 16, 0, 0);
        __builtin_amdgcn_global_load_lds((const __attribute__((address_space(1))) void*)(gB + rowstep),
            (__attribute__((address_space(3))) void*)lB1, 16, 0, 0);
        gA += 64; gB += 64;
        __syncthreads();

        v4i af[4], bf[4];
#pragma unroll
        for (int m = 0; m < 4; ++m)
            af[m] = *reinterpret_cast<const v4i*>(As + a_off + m * 16 * 64);
#pragma unroll
        for (int n = 0; n < 4; ++n)
            bf[n] = *reinterpret_cast<const v4i*>(Bs + b_off + n * 16 * 64);
#pragma unroll
        for (int m = 0; m < 4; ++m)
#pragma unroll
            for (int n = 0; n < 4; ++n)
                acc[m][n] = __builtin_amdgcn_mfma_i32_16x16x64_i8(af[m], bf[n], acc[m][n], 0, 0, 0);
    }
#pragma unroll
    for (int n = 0; n < 4; ++n) {
        const int gcol = tile_n + wc * 64 + n * 16 + fr;
        const float ws = w_s[gcol];
#pragma unroll
        for (int m = 0; m < 4; ++m) {
            const int rbase = tile_m + wr * 64 + m * 16 + fq * 4;
#pragma unroll
            for (int j = 0; j < 4; ++j)
                out[(size_t)(rbase + j) * N + gcol] = (float)acc[m][n][j] * a_s[rbase + j] * ws;
        }
    }
}

// ---------------------------------------------------------------------------
extern "C" void kernel_launch(void* const* d_in, const int* in_sizes, int n_in,
                              void* d_out, int out_size, void* d_ws, size_t ws_size,
                              hipStream_t stream) {
    const float* x      = (const float*)d_in[0];
    const int*   w      = (const int*)d_in[1];      // int8 widened to int32
    const float* wscale = (const float*)d_in[2];

    const int N = in_sizes[2];            // OUT
    const int K = in_sizes[1] / N;        // IN
    const int M = in_sizes[0] / K;        // B*S

    signed char* aq = (signed char*)d_ws;                       // M*K int8
    signed char* wq = aq + (size_t)M * K;                       // N*K int8
    float* as_buf   = (float*)(wq + (size_t)N * K);             // M floats

    const int n4 = (N * K) >> 2;
    pack_w_kernel<<<(n4 + 255) / 256, 256, 0, stream>>>(w, (int*)wq, n4);

    if (K == 4096 && (M & 3) == 0) {
        quant_row4096_kernel<<<M / 4, 256, 0, stream>>>(x, (int*)aq, as_buf);
    } else {
        quant_kernel<<<M, 256, 0, stream>>>(x, (int*)aq, as_buf, K);
    }

    if ((M & 255) == 0 && (N & 255) == 0 && (K & 127) == 0) {
        const int nwg = (M >> 8) * (N >> 8);
        gemm_i8_8p<<<nwg, 512, 0, stream>>>(aq, wq, as_buf, wscale,
                                            (float*)d_out, M, N, K);
    } else {
        dim3 grid(N / 128, M / 128);
        gemm_i8_kernel<<<grid, 256, 0, stream>>>(aq, wq, as_buf, wscale,
                                                 (float*)d_out, M, N, K);
    }
}